// Round 9
// baseline (228.567 us; speedup 1.0000x reference)
//
#include <hip/hip_runtime.h>
#include <hip/hip_bf16.h>

// GCN 2-layer + mean-pool + log_softmax on gfx950.
// R9: agg1+gemm2 fusion kept, but W2/b1 moved from LDS to per-lane REGISTERS
//     (R8's w2s reads were 8-way bank-conflicted: 5.8M conflicts, 57us).
//     Lane (sub,slot) statically needs W2[sub*16+j][2slot(+1)], b1[sub*16+j].

#define NN 50000
#define EE 600000
#define FIN 128
#define HH 128
#define CC 16
#define GG 500
#define ETOT (EE + NN)   // 650000
#define SBLK 196         // ceil(NN/256) scan blocks
#define WTS 140          // gemm1 wt row stride

typedef unsigned short ushort_t;
typedef unsigned int uint_t;

typedef __attribute__((ext_vector_type(8))) short bf16x8;
typedef __attribute__((ext_vector_type(4))) ushort_t u16x4;
typedef __attribute__((ext_vector_type(4))) float f32x4;
typedef __attribute__((ext_vector_type(2))) float f32x2;

__device__ inline ushort_t f2bf(float f) {
    uint_t u = __float_as_uint(f);
    u = (u + 0x7FFFu + ((u >> 16) & 1u)) >> 16;   // RNE
    return (ushort_t)u;
}
__device__ inline float bf2f(ushort_t b) {
    return __uint_as_float(((uint_t)b) << 16);
}
__device__ inline ushort_t f2h(float f) {
    _Float16 h = (_Float16)f; ushort_t u; __builtin_memcpy(&u, &h, 2); return u;
}
__device__ inline float h2f(ushort_t u) {
    _Float16 h; __builtin_memcpy(&h, &u, 2); return (float)h;
}

// ---------------- init ----------------
__global__ void init_kernel(int* cnt, float* pooled) {
    int i = blockIdx.x * blockDim.x + threadIdx.x;
    if (i < NN) cnt[i] = 0;
    if (i < GG * CC) pooled[i] = 0.0f;
}

// ---------------- count: single scattered-atomic pass ----------------
__global__ void count_kernel(const int* __restrict__ edge_dst,
                             int* __restrict__ cnt, int* __restrict__ seq) {
    int idx = blockIdx.x * blockDim.x + threadIdx.x;
    if (idx < EE) seq[idx] = atomicAdd(&cnt[edge_dst[idx]], 1);
}

// ---------------- GEMM1: hb8 = fp8(x @ W1), unscaled ----------------
__global__ __launch_bounds__(256) void gemm1_kernel(const float* __restrict__ x,
                                                    const float* __restrict__ W1,
                                                    unsigned char* __restrict__ hb8) {
    __shared__ ushort_t xs[64 * 136];
    __shared__ ushort_t wt[128 * WTS];
    int t = threadIdx.x;
    int row0 = blockIdx.x * 64;
    for (int i = 0; i < 8; i++) {
        int slot = t + i * 256;
        int r = slot >> 5, k4 = slot & 31;
        int gr = row0 + r;
        float4 v = (gr < NN) ? ((const float4*)x)[gr * 32 + k4]
                             : make_float4(0.f, 0.f, 0.f, 0.f);
        u16x4 bv = { f2bf(v.x), f2bf(v.y), f2bf(v.z), f2bf(v.w) };
        *(u16x4*)(&xs[r * 136 + k4 * 4]) = bv;
    }
    for (int i = 0; i < 16; i++) {
        int idx = t + i * 256;
        int c = idx & 127, k4 = idx >> 7;
        u16x4 bv = { f2bf(W1[(4 * k4 + 0) * HH + c]),
                     f2bf(W1[(4 * k4 + 1) * HH + c]),
                     f2bf(W1[(4 * k4 + 2) * HH + c]),
                     f2bf(W1[(4 * k4 + 3) * HH + c]) };
        *(u16x4*)(&wt[c * WTS + k4 * 4]) = bv;
    }
    __syncthreads();

    int wave = t >> 6, lane = t & 63;
    int m = lane & 15, quad = lane >> 4;
    f32x4 acc[8];
    for (int ct = 0; ct < 8; ct++) acc[ct] = (f32x4)(0.0f);
    for (int ko = 0; ko < 4; ko++) {
        bf16x8 a = *(const bf16x8*)(&xs[(16 * wave + m) * 136 + ko * 32 + quad * 8]);
        for (int ct = 0; ct < 8; ct++) {
            bf16x8 b = *(const bf16x8*)(&wt[(ct * 16 + m) * WTS + ko * 32 + quad * 8]);
            acc[ct] = __builtin_amdgcn_mfma_f32_16x16x32_bf16(a, b, acc[ct], 0, 0, 0);
        }
    }
    for (int ct = 0; ct < 8; ct++) {
        int gcol = ct * 16 + m;
        for (int r = 0; r < 4; r++) {
            int grow = row0 + wave * 16 + quad * 4 + r;
            if (grow < NN) {
                int p = __builtin_amdgcn_cvt_pk_fp8_f32(acc[ct][r], 0.0f, 0, false);
                hb8[(size_t)grow * HH + gcol] = (unsigned char)(p & 0xFF);
            }
        }
    }
}

// ---------------- block-scan helper ----------------
__device__ inline int block_excl_scan(int v, int t, int* total) {
    __shared__ int wsum[4];
    int lane = t & 63, wv = t >> 6;
    int inc = v;
    for (int off = 1; off < 64; off <<= 1) {
        int n = __shfl_up(inc, off);
        if (lane >= off) inc += n;
    }
    if (lane == 63) wsum[wv] = inc;
    __syncthreads();
    int off_w = 0;
    for (int w = 0; w < wv; w++) off_w += wsum[w];
    *total = wsum[0] + wsum[1] + wsum[2] + wsum[3];
    return off_w + inc - v;
}

// ---------------- scan A ----------------
__global__ __launch_bounds__(256) void scanA_kernel(const int* __restrict__ cnt,
                                                    int* __restrict__ rowptr,
                                                    float* __restrict__ dis,
                                                    int* __restrict__ bsum) {
    int t = threadIdx.x;
    int i = blockIdx.x * 256 + t;
    int d = 0;
    if (i < NN) {
        d = cnt[i] + 1;                        // +1 self-loop
        dis[i] = rsqrtf((float)d);
    }
    int total;
    int excl = block_excl_scan(d, t, &total);
    if (i < NN) rowptr[i] = excl;
    if (t == 0) bsum[blockIdx.x] = total;
}

// ---------------- scan BC ----------------
__global__ __launch_bounds__(256) void scanBC_kernel(int* __restrict__ rowptr,
                                                     const int* __restrict__ bsum) {
    __shared__ int sb[256];
    int t = threadIdx.x;
    int v = (t < SBLK) ? bsum[t] : 0;
    int total;
    int ex = block_excl_scan(v, t, &total);
    sb[t] = ex;
    __syncthreads();
    int myoff = sb[blockIdx.x];
    int i = blockIdx.x * 256 + t;
    if (i < NN) rowptr[i] += myoff;
    if (blockIdx.x == 0 && t == 0) rowptr[NN] = ETOT;
}

// ---------------- CSR fill: entry = src | fp16(dis[src])<<16 ----------------
__global__ void fill_kernel(const int* __restrict__ edge_src,
                            const int* __restrict__ edge_dst,
                            const float* __restrict__ dis,
                            const int* __restrict__ rowptr,
                            const int* __restrict__ seq,
                            uint_t* __restrict__ csr) {
    int idx = blockIdx.x * blockDim.x + threadIdx.x;
    if (idx < EE) {
        int s = edge_src[idx], d = edge_dst[idx];
        csr[rowptr[d] + seq[idx]] = (uint_t)s | ((uint_t)f2h(dis[s]) << 16);
    } else if (idx < ETOT) {
        int n = idx - EE;
        csr[rowptr[n + 1] - 1] = (uint_t)n | ((uint_t)f2h(dis[n]) << 16);
    }
}

// ---------------- agg1 + gemm2 fused (W2/b1 in registers) ----------------
__global__ __launch_bounds__(256) void agg1_kernel(const unsigned char* __restrict__ hb8,
                                                   const int* __restrict__ rowptr,
                                                   const uint_t* __restrict__ csr,
                                                   const float* __restrict__ dis,
                                                   const float* __restrict__ b1,
                                                   const float* __restrict__ W2,
                                                   ushort_t* __restrict__ h2b) {
    int t = threadIdx.x;
    int wave = t >> 6, lane = t & 63;
    int slot = lane >> 3, sub = lane & 7;
    // per-lane static W2/b1 fragments (L2-resident reads, once per thread)
    float w2r0[16], w2r1[16], b1r[16];
    for (int j = 0; j < 16; j++) {
        int k = sub * 16 + j;
        w2r0[j] = W2[k * CC + 2 * slot];
        w2r1[j] = W2[k * CC + 2 * slot + 1];
        b1r[j]  = b1[k];
    }
    for (int it = 0; it < 4; it++) {
        int node = blockIdx.x * 16 + wave * 4 + it;
        int e0 = rowptr[node], e1 = rowptr[node + 1];
        float acc[16];
        for (int j = 0; j < 16; j++) acc[j] = 0.0f;
        for (int e = e0 + slot; e < e1; e += 8) {
            uint_t ent = csr[e];
            float w = h2f((ushort_t)(ent >> 16));
            uint4 hv = *(const uint4*)(hb8 + (size_t)(ent & 0xFFFFu) * HH + sub * 16);
            uint_t words[4] = { hv.x, hv.y, hv.z, hv.w };
            for (int q = 0; q < 4; q++) {
                f32x2 lo = __builtin_amdgcn_cvt_pk_f32_fp8(words[q], false);
                f32x2 hi = __builtin_amdgcn_cvt_pk_f32_fp8(words[q], true);
                acc[q * 4 + 0] += w * lo[0];
                acc[q * 4 + 1] += w * lo[1];
                acc[q * 4 + 2] += w * hi[0];
                acc[q * 4 + 3] += w * hi[1];
            }
        }
        for (int j = 0; j < 16; j++) {
            acc[j] += __shfl_xor(acc[j], 8);
            acc[j] += __shfl_xor(acc[j], 16);
            acc[j] += __shfl_xor(acc[j], 32);
        }
        // relu + gemm2 fragment, all in registers
        float dn = dis[node];
        float p0 = 0.0f, p1 = 0.0f;
        for (int j = 0; j < 16; j++) {
            float hv = fmaxf(dn * acc[j] + b1r[j], 0.0f);
            p0 += hv * w2r0[j];
            p1 += hv * w2r1[j];
        }
        p0 += __shfl_xor(p0, 1); p0 += __shfl_xor(p0, 2); p0 += __shfl_xor(p0, 4);
        p1 += __shfl_xor(p1, 1); p1 += __shfl_xor(p1, 2); p1 += __shfl_xor(p1, 4);
        if (sub == 0) {
            uint_t packed = (uint_t)f2bf(p0) | ((uint_t)f2bf(p1) << 16);
            *(uint_t*)(h2b + (size_t)node * CC + 2 * slot) = packed;
        }
    }
}

// ---------------- agg2 + pool fused, sorted-batch segmented flush ----------------
__global__ __launch_bounds__(256) void agg2pool_kernel(const ushort_t* __restrict__ h2b,
                                                       const int* __restrict__ rowptr,
                                                       const uint_t* __restrict__ csr,
                                                       const float* __restrict__ dis,
                                                       const float* __restrict__ b2,
                                                       const int* __restrict__ batch,
                                                       float* __restrict__ pooled) {
    __shared__ float vals[16][16];
    __shared__ int gid[16];
    int t = threadIdx.x;
    int local = t >> 4, c = t & 15;
    int node = blockIdx.x * 16 + local;
    int e0 = rowptr[node], e1 = rowptr[node + 1];
    float acc = 0.0f;
    for (int e = e0; e < e1; e++) {
        uint_t ent = csr[e];
        acc += h2f((ushort_t)(ent >> 16)) * bf2f(h2b[(size_t)(ent & 0xFFFFu) * CC + c]);
    }
    vals[local][c] = acc * dis[node] + b2[c];
    if (c == 0) gid[local] = batch[node];
    __syncthreads();
    if (t < 16) {                      // walker for channel t
        float run = 0.0f;
        for (int i = 0; i < 16; i++) {
            run += vals[i][t];
            if (i == 15 || gid[i + 1] != gid[i]) {
                atomicAdd(&pooled[gid[i] * CC + t], run);
                run = 0.0f;
            }
        }
    }
}

// ---------------- mean + log_softmax (counts via binary search) ----------------
__global__ void lsm_kernel(const float* __restrict__ pooled,
                           const int* __restrict__ batch,
                           float* __restrict__ out) {
    int idx = blockIdx.x * blockDim.x + threadIdx.x;
    int g = idx >> 4, c = idx & 15;
    if (g >= GG) return;
    int lo = 0, hi = NN;
    while (lo < hi) { int mid = (lo + hi) >> 1; if (batch[mid] < g) lo = mid + 1; else hi = mid; }
    int lo2 = lo, hi2 = NN;
    while (lo2 < hi2) { int mid = (lo2 + hi2) >> 1; if (batch[mid] < g + 1) lo2 = mid + 1; else hi2 = mid; }
    float cnt = (float)(lo2 - lo);
    float v = pooled[g * CC + c] / fmaxf(cnt, 1.0f);
    float m = v;
    for (int off = 8; off >= 1; off >>= 1) m = fmaxf(m, __shfl_xor(m, off, 16));
    float s = expf(v - m);
    for (int off = 8; off >= 1; off >>= 1) s += __shfl_xor(s, off, 16);
    out[g * CC + c] = v - m - logf(s);
}

extern "C" void kernel_launch(void* const* d_in, const int* in_sizes, int n_in,
                              void* d_out, int out_size, void* d_ws, size_t ws_size,
                              hipStream_t stream) {
    const float* x  = (const float*)d_in[0];
    const float* W1 = (const float*)d_in[1];
    const float* b1 = (const float*)d_in[2];
    const float* W2 = (const float*)d_in[3];
    const float* b2 = (const float*)d_in[4];
    const int* edge_src = (const int*)d_in[5];
    const int* edge_dst = (const int*)d_in[6];
    const int* batch    = (const int*)d_in[7];
    float* out = (float*)d_out;

    char* ws = (char*)d_ws;
    size_t off = 0;
    auto alloc = [&](size_t bytes) {
        void* p = ws + off;
        off += (bytes + 255) & ~size_t(255);
        return p;
    };
    int*   cnt     = (int*)  alloc(NN * 4);
    float* dis     = (float*)alloc(NN * 4);
    int*   rowptr  = (int*)  alloc((NN + 1) * 4);
    int*   seq     = (int*)  alloc(EE * 4);
    int*   bsum    = (int*)  alloc(SBLK * 4);
    uint_t* csr    = (uint_t*)alloc((size_t)ETOT * 4);
    unsigned char* hb8 = (unsigned char*)alloc((size_t)NN * HH);
    ushort_t* h2b  = (ushort_t*)alloc((size_t)NN * CC * 2);
    float* pooled  = (float*)alloc(GG * CC * 4);

    const int B = 256;
    init_kernel<<<(NN + B - 1) / B, B, 0, stream>>>(cnt, pooled);
    count_kernel<<<(EE + B - 1) / B, B, 0, stream>>>(edge_dst, cnt, seq);
    gemm1_kernel<<<(NN + 63) / 64, B, 0, stream>>>(x, W1, hb8);
    scanA_kernel<<<SBLK, B, 0, stream>>>(cnt, rowptr, dis, bsum);
    scanBC_kernel<<<SBLK, B, 0, stream>>>(rowptr, bsum);
    fill_kernel<<<(ETOT + B - 1) / B, B, 0, stream>>>(edge_src, edge_dst, dis,
                                                      rowptr, seq, csr);
    agg1_kernel<<<NN / 16, B, 0, stream>>>(hb8, rowptr, csr, dis, b1, W2, h2b);
    agg2pool_kernel<<<NN / 16, B, 0, stream>>>(h2b, rowptr, csr, dis, b2, batch, pooled);
    lsm_kernel<<<(GG * CC + B - 1) / B, B, 0, stream>>>(pooled, batch, out);
}

// Round 10
// 202.460 us; speedup vs baseline: 1.1289x; 1.1289x over previous
//
#include <hip/hip_runtime.h>
#include <hip/hip_bf16.h>

// GCN 2-layer + mean-pool + log_softmax on gfx950.
// R10: revert agg1 to 1 node/wave (R7-R9 fusion serialized 4 nodes/wave and
//      lost MLP on a latency-bound gather; R9's reg-array W2 spilled to
//      scratch). Standalone MFMA gemm2 with transposed-W2 LDS (b128 frags).
//      agg2pool: 1024-thr blocks, 1 node/wave, 4B loads, 2-deep pipeline.

#define NN 50000
#define EE 600000
#define FIN 128
#define HH 128
#define CC 16
#define GG 500
#define ETOT (EE + NN)   // 650000
#define SBLK 196         // ceil(NN/256) scan blocks
#define WTS 140          // gemm1 wt row stride

typedef unsigned short ushort_t;
typedef unsigned int uint_t;

typedef __attribute__((ext_vector_type(8))) short bf16x8;
typedef __attribute__((ext_vector_type(8))) ushort_t u16x8;
typedef __attribute__((ext_vector_type(4))) ushort_t u16x4;
typedef __attribute__((ext_vector_type(4))) float f32x4;
typedef __attribute__((ext_vector_type(2))) float f32x2;

__device__ inline ushort_t f2bf(float f) {
    uint_t u = __float_as_uint(f);
    u = (u + 0x7FFFu + ((u >> 16) & 1u)) >> 16;   // RNE
    return (ushort_t)u;
}
__device__ inline float bf2f(ushort_t b) {
    return __uint_as_float(((uint_t)b) << 16);
}
__device__ inline ushort_t f2h(float f) {
    _Float16 h = (_Float16)f; ushort_t u; __builtin_memcpy(&u, &h, 2); return u;
}
__device__ inline float h2f(ushort_t u) {
    _Float16 h; __builtin_memcpy(&h, &u, 2); return (float)h;
}

// ---------------- init ----------------
__global__ void init_kernel(int* cnt, float* pooled) {
    int i = blockIdx.x * blockDim.x + threadIdx.x;
    if (i < NN) cnt[i] = 0;
    if (i < GG * CC) pooled[i] = 0.0f;
}

// ---------------- count: single scattered-atomic pass ----------------
__global__ void count_kernel(const int* __restrict__ edge_dst,
                             int* __restrict__ cnt, int* __restrict__ seq) {
    int idx = blockIdx.x * blockDim.x + threadIdx.x;
    if (idx < EE) seq[idx] = atomicAdd(&cnt[edge_dst[idx]], 1);
}

// ---------------- GEMM1: hb8 = fp8(x @ W1), unscaled ----------------
__global__ __launch_bounds__(256) void gemm1_kernel(const float* __restrict__ x,
                                                    const float* __restrict__ W1,
                                                    unsigned char* __restrict__ hb8) {
    __shared__ ushort_t xs[64 * 136];
    __shared__ ushort_t wt[128 * WTS];
    int t = threadIdx.x;
    int row0 = blockIdx.x * 64;
    for (int i = 0; i < 8; i++) {
        int slot = t + i * 256;
        int r = slot >> 5, k4 = slot & 31;
        int gr = row0 + r;
        float4 v = (gr < NN) ? ((const float4*)x)[gr * 32 + k4]
                             : make_float4(0.f, 0.f, 0.f, 0.f);
        u16x4 bv = { f2bf(v.x), f2bf(v.y), f2bf(v.z), f2bf(v.w) };
        *(u16x4*)(&xs[r * 136 + k4 * 4]) = bv;
    }
    for (int i = 0; i < 16; i++) {
        int idx = t + i * 256;
        int c = idx & 127, k4 = idx >> 7;
        u16x4 bv = { f2bf(W1[(4 * k4 + 0) * HH + c]),
                     f2bf(W1[(4 * k4 + 1) * HH + c]),
                     f2bf(W1[(4 * k4 + 2) * HH + c]),
                     f2bf(W1[(4 * k4 + 3) * HH + c]) };
        *(u16x4*)(&wt[c * WTS + k4 * 4]) = bv;
    }
    __syncthreads();

    int wave = t >> 6, lane = t & 63;
    int m = lane & 15, quad = lane >> 4;
    f32x4 acc[8];
    for (int ct = 0; ct < 8; ct++) acc[ct] = (f32x4)(0.0f);
    for (int ko = 0; ko < 4; ko++) {
        bf16x8 a = *(const bf16x8*)(&xs[(16 * wave + m) * 136 + ko * 32 + quad * 8]);
        for (int ct = 0; ct < 8; ct++) {
            bf16x8 b = *(const bf16x8*)(&wt[(ct * 16 + m) * WTS + ko * 32 + quad * 8]);
            acc[ct] = __builtin_amdgcn_mfma_f32_16x16x32_bf16(a, b, acc[ct], 0, 0, 0);
        }
    }
    for (int ct = 0; ct < 8; ct++) {
        int gcol = ct * 16 + m;
        for (int r = 0; r < 4; r++) {
            int grow = row0 + wave * 16 + quad * 4 + r;
            if (grow < NN) {
                int p = __builtin_amdgcn_cvt_pk_fp8_f32(acc[ct][r], 0.0f, 0, false);
                hb8[(size_t)grow * HH + gcol] = (unsigned char)(p & 0xFF);
            }
        }
    }
}

// ---------------- block-scan helper ----------------
__device__ inline int block_excl_scan(int v, int t, int* total) {
    __shared__ int wsum[4];
    int lane = t & 63, wv = t >> 6;
    int inc = v;
    for (int off = 1; off < 64; off <<= 1) {
        int n = __shfl_up(inc, off);
        if (lane >= off) inc += n;
    }
    if (lane == 63) wsum[wv] = inc;
    __syncthreads();
    int off_w = 0;
    for (int w = 0; w < wv; w++) off_w += wsum[w];
    *total = wsum[0] + wsum[1] + wsum[2] + wsum[3];
    return off_w + inc - v;
}

// ---------------- scan A ----------------
__global__ __launch_bounds__(256) void scanA_kernel(const int* __restrict__ cnt,
                                                    int* __restrict__ rowptr,
                                                    float* __restrict__ dis,
                                                    int* __restrict__ bsum) {
    int t = threadIdx.x;
    int i = blockIdx.x * 256 + t;
    int d = 0;
    if (i < NN) {
        d = cnt[i] + 1;                        // +1 self-loop
        dis[i] = rsqrtf((float)d);
    }
    int total;
    int excl = block_excl_scan(d, t, &total);
    if (i < NN) rowptr[i] = excl;
    if (t == 0) bsum[blockIdx.x] = total;
}

// ---------------- scan BC ----------------
__global__ __launch_bounds__(256) void scanBC_kernel(int* __restrict__ rowptr,
                                                     const int* __restrict__ bsum) {
    __shared__ int sb[256];
    int t = threadIdx.x;
    int v = (t < SBLK) ? bsum[t] : 0;
    int total;
    int ex = block_excl_scan(v, t, &total);
    sb[t] = ex;
    __syncthreads();
    int myoff = sb[blockIdx.x];
    int i = blockIdx.x * 256 + t;
    if (i < NN) rowptr[i] += myoff;
    if (blockIdx.x == 0 && t == 0) rowptr[NN] = ETOT;
}

// ---------------- CSR fill: entry = src | fp16(dis[src])<<16 ----------------
__global__ void fill_kernel(const int* __restrict__ edge_src,
                            const int* __restrict__ edge_dst,
                            const float* __restrict__ dis,
                            const int* __restrict__ rowptr,
                            const int* __restrict__ seq,
                            uint_t* __restrict__ csr) {
    int idx = blockIdx.x * blockDim.x + threadIdx.x;
    if (idx < EE) {
        int s = edge_src[idx], d = edge_dst[idx];
        csr[rowptr[d] + seq[idx]] = (uint_t)s | ((uint_t)f2h(dis[s]) << 16);
    } else if (idx < ETOT) {
        int n = idx - EE;
        csr[rowptr[n + 1] - 1] = (uint_t)n | ((uint_t)f2h(dis[n]) << 16);
    }
}

// ---------------- agg1: h1b = bf16(relu(dis[d]*segsum(w*fp8row) + b1)) --------
// 1 node/wave, 8 edge slots x 8 feature-lanes, 2-deep load pipeline.
__global__ __launch_bounds__(256) void agg1_kernel(const unsigned char* __restrict__ hb8,
                                                   const int* __restrict__ rowptr,
                                                   const uint_t* __restrict__ csr,
                                                   const float* __restrict__ dis,
                                                   const float* __restrict__ b1,
                                                   ushort_t* __restrict__ h1b) {
    int wave = threadIdx.x >> 6, lane = threadIdx.x & 63;
    int node = blockIdx.x * 4 + wave;
    int slot = lane >> 3, sub = lane & 7;
    int e0 = rowptr[node], e1 = rowptr[node + 1];
    float acc[16];
    for (int j = 0; j < 16; j++) acc[j] = 0.0f;
    for (int e = e0 + slot; e < e1; e += 16) {
        // fetch both csr entries first, then both row gathers (2-deep MLP)
        uint_t ent0 = csr[e];
        bool has2 = (e + 8) < e1;
        uint_t ent1 = has2 ? csr[e + 8] : ent0;
        uint4 hv0 = *(const uint4*)(hb8 + (size_t)(ent0 & 0xFFFFu) * HH + sub * 16);
        uint4 hv1 = has2 ? *(const uint4*)(hb8 + (size_t)(ent1 & 0xFFFFu) * HH + sub * 16)
                         : make_uint4(0, 0, 0, 0);
        float w0 = h2f((ushort_t)(ent0 >> 16));
        uint_t words0[4] = { hv0.x, hv0.y, hv0.z, hv0.w };
        for (int q = 0; q < 4; q++) {
            f32x2 lo = __builtin_amdgcn_cvt_pk_f32_fp8(words0[q], false);
            f32x2 hi = __builtin_amdgcn_cvt_pk_f32_fp8(words0[q], true);
            acc[q * 4 + 0] += w0 * lo[0];
            acc[q * 4 + 1] += w0 * lo[1];
            acc[q * 4 + 2] += w0 * hi[0];
            acc[q * 4 + 3] += w0 * hi[1];
        }
        if (has2) {
            float w1 = h2f((ushort_t)(ent1 >> 16));
            uint_t words1[4] = { hv1.x, hv1.y, hv1.z, hv1.w };
            for (int q = 0; q < 4; q++) {
                f32x2 lo = __builtin_amdgcn_cvt_pk_f32_fp8(words1[q], false);
                f32x2 hi = __builtin_amdgcn_cvt_pk_f32_fp8(words1[q], true);
                acc[q * 4 + 0] += w1 * lo[0];
                acc[q * 4 + 1] += w1 * lo[1];
                acc[q * 4 + 2] += w1 * hi[0];
                acc[q * 4 + 3] += w1 * hi[1];
            }
        }
    }
    for (int j = 0; j < 16; j++) {
        acc[j] += __shfl_xor(acc[j], 8);
        acc[j] += __shfl_xor(acc[j], 16);
        acc[j] += __shfl_xor(acc[j], 32);
    }
    if (slot == 0) {
        float dn = dis[node];
        const float4* b1v = (const float4*)(b1 + sub * 16);
        float4 bb[4] = { b1v[0], b1v[1], b1v[2], b1v[3] };
        const float* bbf = (const float*)bb;
        u16x8 o0, o1;
        for (int j = 0; j < 8; j++) {
            o0[j] = f2bf(fmaxf(dn * acc[j]     + bbf[j],     0.0f));
            o1[j] = f2bf(fmaxf(dn * acc[8 + j] + bbf[8 + j], 0.0f));
        }
        *(u16x8*)(h1b + (size_t)node * HH + sub * 16)     = o0;
        *(u16x8*)(h1b + (size_t)node * HH + sub * 16 + 8) = o1;
    }
}

// ---------------- GEMM2: h2b = bf16(h1b @ W2), unscaled ----------------
// W2 staged TRANSPOSED in LDS (w2t[m][k], stride 132) -> B frag = 1 ds_read_b128.
__global__ __launch_bounds__(256) void gemm2_kernel(const ushort_t* __restrict__ h1b,
                                                    const float* __restrict__ W2,
                                                    ushort_t* __restrict__ h2b) {
    __shared__ ushort_t w2t[CC * 132];   // [m][k] bf16
    int t = threadIdx.x;
    for (int i = t; i < HH * CC; i += 256) {
        int k = i >> 4, m = i & 15;
        w2t[m * 132 + k] = f2bf(W2[i]);
    }
    __syncthreads();
    int wave = t >> 6, lane = t & 63;
    int m = lane & 15, quad = lane >> 4;
    int node0 = (blockIdx.x * 4 + wave) * 16;
    f32x4 acc = (f32x4)(0.0f);
    int arow = node0 + m;
    for (int ko = 0; ko < 4; ko++) {
        bf16x8 a = *(const bf16x8*)(h1b + (size_t)arow * HH + ko * 32 + quad * 8);
        bf16x8 b = *(const bf16x8*)(&w2t[m * 132 + ko * 32 + quad * 8]);
        acc = __builtin_amdgcn_mfma_f32_16x16x32_bf16(a, b, acc, 0, 0, 0);
    }
    for (int r = 0; r < 4; r++) {
        int grow = node0 + quad * 4 + r;
        h2b[(size_t)grow * CC + m] = f2bf(acc[r]);
    }
}

// ---------------- agg2 + pool: 1 node/wave, 16 nodes/block (1024 thr) ---------
__global__ __launch_bounds__(1024) void agg2pool_kernel(const ushort_t* __restrict__ h2b,
                                                        const int* __restrict__ rowptr,
                                                        const uint_t* __restrict__ csr,
                                                        const float* __restrict__ dis,
                                                        const float* __restrict__ b2,
                                                        const int* __restrict__ batch,
                                                        float* __restrict__ pooled) {
    __shared__ float vals[16][16];
    __shared__ int gid[16];
    int wave = threadIdx.x >> 6, lane = threadIdx.x & 63;
    int node = blockIdx.x * 16 + wave;
    int slot = lane >> 3, sub = lane & 7;
    int e0 = rowptr[node], e1 = rowptr[node + 1];
    float a0 = 0.0f, a1 = 0.0f;
    for (int e = e0 + slot; e < e1; e += 16) {
        uint_t ent0 = csr[e];
        bool has2 = (e + 8) < e1;
        uint_t ent1 = has2 ? csr[e + 8] : ent0;
        uint_t p0 = *(const uint_t*)(h2b + (size_t)(ent0 & 0xFFFFu) * CC + sub * 2);
        uint_t p1 = has2 ? *(const uint_t*)(h2b + (size_t)(ent1 & 0xFFFFu) * CC + sub * 2) : 0;
        float w0 = h2f((ushort_t)(ent0 >> 16));
        a0 += w0 * bf2f((ushort_t)(p0 & 0xFFFFu));
        a1 += w0 * bf2f((ushort_t)(p0 >> 16));
        if (has2) {
            float w1 = h2f((ushort_t)(ent1 >> 16));
            a0 += w1 * bf2f((ushort_t)(p1 & 0xFFFFu));
            a1 += w1 * bf2f((ushort_t)(p1 >> 16));
        }
    }
    a0 += __shfl_xor(a0, 8); a0 += __shfl_xor(a0, 16); a0 += __shfl_xor(a0, 32);
    a1 += __shfl_xor(a1, 8); a1 += __shfl_xor(a1, 16); a1 += __shfl_xor(a1, 32);
    if (slot == 0) {
        float dn = dis[node];
        vals[wave][2 * sub]     = a0 * dn + b2[2 * sub];
        vals[wave][2 * sub + 1] = a1 * dn + b2[2 * sub + 1];
        if (sub == 0) gid[wave] = batch[node];
    }
    __syncthreads();
    if (threadIdx.x < 16) {            // walker for channel threadIdx.x
        int c = threadIdx.x;
        float run = 0.0f;
        for (int i = 0; i < 16; i++) {
            run += vals[i][c];
            if (i == 15 || gid[i + 1] != gid[i]) {
                atomicAdd(&pooled[gid[i] * CC + c], run);
                run = 0.0f;
            }
        }
    }
}

// ---------------- mean + log_softmax (counts via binary search) ----------------
__global__ void lsm_kernel(const float* __restrict__ pooled,
                           const int* __restrict__ batch,
                           float* __restrict__ out) {
    int idx = blockIdx.x * blockDim.x + threadIdx.x;
    int g = idx >> 4, c = idx & 15;
    if (g >= GG) return;
    int lo = 0, hi = NN;
    while (lo < hi) { int mid = (lo + hi) >> 1; if (batch[mid] < g) lo = mid + 1; else hi = mid; }
    int lo2 = lo, hi2 = NN;
    while (lo2 < hi2) { int mid = (lo2 + hi2) >> 1; if (batch[mid] < g + 1) lo2 = mid + 1; else hi2 = mid; }
    float cnt = (float)(lo2 - lo);
    float v = pooled[g * CC + c] / fmaxf(cnt, 1.0f);
    float m = v;
    for (int off = 8; off >= 1; off >>= 1) m = fmaxf(m, __shfl_xor(m, off, 16));
    float s = expf(v - m);
    for (int off = 8; off >= 1; off >>= 1) s += __shfl_xor(s, off, 16);
    out[g * CC + c] = v - m - logf(s);
}

extern "C" void kernel_launch(void* const* d_in, const int* in_sizes, int n_in,
                              void* d_out, int out_size, void* d_ws, size_t ws_size,
                              hipStream_t stream) {
    const float* x  = (const float*)d_in[0];
    const float* W1 = (const float*)d_in[1];
    const float* b1 = (const float*)d_in[2];
    const float* W2 = (const float*)d_in[3];
    const float* b2 = (const float*)d_in[4];
    const int* edge_src = (const int*)d_in[5];
    const int* edge_dst = (const int*)d_in[6];
    const int* batch    = (const int*)d_in[7];
    float* out = (float*)d_out;

    char* ws = (char*)d_ws;
    size_t off = 0;
    auto alloc = [&](size_t bytes) {
        void* p = ws + off;
        off += (bytes + 255) & ~size_t(255);
        return p;
    };
    int*   cnt     = (int*)  alloc(NN * 4);
    float* dis     = (float*)alloc(NN * 4);
    int*   rowptr  = (int*)  alloc((NN + 1) * 4);
    int*   seq     = (int*)  alloc(EE * 4);
    int*   bsum    = (int*)  alloc(SBLK * 4);
    uint_t* csr    = (uint_t*)alloc((size_t)ETOT * 4);
    unsigned char* hb8 = (unsigned char*)alloc((size_t)NN * HH);
    ushort_t* h1b  = (ushort_t*)alloc((size_t)NN * HH * 2);
    ushort_t* h2b  = (ushort_t*)alloc((size_t)NN * CC * 2);
    float* pooled  = (float*)alloc(GG * CC * 4);

    const int B = 256;
    init_kernel<<<(NN + B - 1) / B, B, 0, stream>>>(cnt, pooled);
    count_kernel<<<(EE + B - 1) / B, B, 0, stream>>>(edge_dst, cnt, seq);
    gemm1_kernel<<<(NN + 63) / 64, B, 0, stream>>>(x, W1, hb8);
    scanA_kernel<<<SBLK, B, 0, stream>>>(cnt, rowptr, dis, bsum);
    scanBC_kernel<<<SBLK, B, 0, stream>>>(rowptr, bsum);
    fill_kernel<<<(ETOT + B - 1) / B, B, 0, stream>>>(edge_src, edge_dst, dis,
                                                      rowptr, seq, csr);
    agg1_kernel<<<NN / 4, B, 0, stream>>>(hb8, rowptr, csr, dis, b1, h1b);
    gemm2_kernel<<<(NN + 63) / 64, B, 0, stream>>>(h1b, W2, h2b);
    agg2pool_kernel<<<NN / 16, 1024, 0, stream>>>(h2b, rowptr, csr, dis, b2, batch, pooled);
    lsm_kernel<<<(GG * CC + B - 1) / B, B, 0, stream>>>(pooled, batch, out);
}